// Round 9
// baseline (237.178 us; speedup 1.0000x reference)
//
#include <hip/hip_runtime.h>

#define T_STEPS 512
#define HID 64
#define SPB 8
#define NT 512

typedef _Float16 f16x8 __attribute__((ext_vector_type(8)));
typedef float f32x4 __attribute__((ext_vector_type(4)));

#define MFMA(a, b, c) __builtin_amdgcn_mfma_f32_16x16x32_f16(a, b, c, 0, 0, 0)

#define LOG2E 1.44269504088896340736f

// pack two floats -> 2x fp16 dword (RNE scalar converts)
__device__ __forceinline__ unsigned pkh(float a, float b) {
    unsigned short ua = __builtin_bit_cast(unsigned short, (_Float16)a);
    unsigned short ub = __builtin_bit_cast(unsigned short, (_Float16)b);
    return (unsigned)ua | ((unsigned)ub << 16);
}
// lane <- lane^8 within each 16-lane row (full-rate VALU DPP row_ror:8)
__device__ __forceinline__ float dpp_ror8(float x) {
    int i = __builtin_bit_cast(int, x);
    int r = __builtin_amdgcn_mov_dpp(i, 0x128, 0xF, 0xF, true);
    return __builtin_bit_cast(float, r);
}
// LDS byte address for [sample][k] fp16 rows of 128B, XOR-swizzled (T2)
__device__ __forceinline__ char* swz(const void* base, int s, int kbyte) {
    int off = s * 128 + kbyte;
    off ^= (s & 7) << 4;
    return (char*)base + off;
}
// gather 8 consecutive fp32, scale, -> f16x8 fragment (init path, RNE)
__device__ __forceinline__ f16x8 g8rowS(const float* __restrict__ p, float s) {
    f16x8 r;
#pragma unroll
    for (int j = 0; j < 8; ++j) r[j] = (_Float16)(p[j] * s);
    return r;
}

// raw barrier: LDS drained, NO vmcnt drain (x prefetch stays in flight)
#define BAR() do { asm volatile("s_waitcnt lgkmcnt(0)" ::: "memory"); \
                   __builtin_amdgcn_s_barrier();                      \
                   asm volatile("" ::: "memory"); } while (0)

__global__ __launch_bounds__(NT, 1)
void gru2_h16(const float* __restrict__ state,
              const float* __restrict__ w_ih1, const float* __restrict__ w_hh1,
              const float* __restrict__ b_ih1, const float* __restrict__ b_hh1,
              const float* __restrict__ w_ih2, const float* __restrict__ w_hh2,
              const float* __restrict__ b_ih2, const float* __restrict__ b_hh2,
              const float* __restrict__ fc_w,  const float* __restrict__ fc_b,
              float* __restrict__ out)
{
    __shared__ __align__(16) unsigned short xb[2][16][64];
    __shared__ __align__(16) unsigned short h1b[2][16][64];
    __shared__ __align__(16) unsigned short h2b[2][16][64];

    const int tid  = threadIdx.x;
    const int wv8  = tid >> 6;
    const bool isA = wv8 < 4;         // waves 0-3: layer1 @ t ; 4-7: layer2 @ t-1
    const int w    = wv8 & 3;
    const int lane = tid & 63;
    const int i16  = lane & 15;
    const int g    = lane >> 4;
    const int g8   = g * 8;
    const int b0   = blockIdx.x * SPB;
    const bool realc = (i16 < 8);     // this lane's MFMA column is a real sample

    const float* Wp = isA ? w_ih1 : w_ih2;
    const float* Wq = isA ? w_hh1 : w_hh2;
    const float* Bi = isA ? b_ih1 : b_ih2;
    const float* Bh = isA ? b_hh1 : b_hh2;

    // resident weight A-fragments, exp-scale folded in
    const int rA = (16 * w + i16) * HID;
    const int zA = rA + 64 * HID;
    const int nA = rA + 128 * HID;
    f16x8 ar[4], az[4], ani[2], anh[2];
    ar[0]  = g8rowS(Wp + rA + g8, -LOG2E);  ar[1]  = g8rowS(Wp + rA + 32 + g8, -LOG2E);
    ar[2]  = g8rowS(Wq + rA + g8, -LOG2E);  ar[3]  = g8rowS(Wq + rA + 32 + g8, -LOG2E);
    az[0]  = g8rowS(Wp + zA + g8, -LOG2E);  az[1]  = g8rowS(Wp + zA + 32 + g8, -LOG2E);
    az[2]  = g8rowS(Wq + zA + g8, -LOG2E);  az[3]  = g8rowS(Wq + zA + 32 + g8, -LOG2E);
    ani[0] = g8rowS(Wp + nA + g8, 2.0f * LOG2E);
    ani[1] = g8rowS(Wp + nA + 32 + g8, 2.0f * LOG2E);
    anh[0] = g8rowS(Wq + nA + g8, 2.0f * LOG2E);
    anh[1] = g8rowS(Wq + nA + 32 + g8, 2.0f * LOG2E);

    // biases as D-layout f32x4 C-init (per-row; neighbor lanes inherit correct rows)
    f32x4 bR4, bZ4, bNi4, bNh4;
#pragma unroll
    for (int q = 0; q < 4; ++q) {
        const int r0 = 16 * w + 4 * g + q;
        bR4[q]  = -LOG2E * (Bi[r0] + Bh[r0]);
        bZ4[q]  = -LOG2E * (Bi[64 + r0] + Bh[64 + r0]);
        bNi4[q] = 2.0f * LOG2E * Bi[128 + r0];
        bNh4[q] = 2.0f * LOG2E * Bh[128 + r0];
    }

    // ---- precomputed LDS addresses (parity-indexed) ----
    // reads: B-fragments (realc lanes only). writes: per-lane 1 dword, 2 rows.
    char* rp[2][2]; char* rq[2][2]; char* wd[2]; char* sa[2];
    const int scol = i16 & 7;                 // real sample column this lane owns
    const int qb4  = realc ? 0 : 4;           // byte offset: rows {0,1} or {2,3}
#pragma unroll
    for (int c = 0; c < 2; ++c) {
        const void* Pb = isA ? (const void*)xb[c]      : (const void*)h1b[c ^ 1];
        const void* Qb = isA ? (const void*)h1b[c ^ 1] : (const void*)h2b[c];
        void* Db       = isA ? (void*)h1b[c]           : (void*)h2b[c ^ 1];
        rp[c][0] = swz(Pb, i16, 16 * g);
        rp[c][1] = swz(Pb, i16, 64 + 16 * g);
        rq[c][0] = swz(Qb, i16, 16 * g);
        rq[c][1] = swz(Qb, i16, 64 + 16 * g);
        wd[c]    = swz(Db, scol, 32 * w + 8 * g + qb4);
        sa[c]    = swz(xb[c ^ 1], (tid >> 5) & 7, (tid & 31) * 4);
    }

    // zero LDS, then stage x(0), prefetch x(1)
    for (int k = tid; k < 2 * 16 * 64; k += NT) {
        ((unsigned short*)xb)[k]  = 0;
        ((unsigned short*)h1b)[k] = 0;
        ((unsigned short*)h2b)[k] = 0;
    }
    __syncthreads();

    const int ss = (tid >> 5) & 7;
    const int sk = (tid & 31) * 2;
    const float* xgp = state + (size_t)(b0 + ss) * T_STEPS * HID + sk;
    float2 PF = make_float2(0.0f, 0.0f);
    if (tid < 256) {
        float2 v0 = *(const float2*)xgp;
        *(unsigned*)swz(xb[0], ss, sk * 2) = pkh(v0.x, v0.y);
        PF = *(const float2*)(xgp + HID);          // x(1) in flight
    }
    const float* xnext = xgp + 2 * HID;            // x(2) next
    __syncthreads();

    float hr0 = 0.0f, hr1 = 0.0f;   // this lane's 2 h rows (rows qb..qb+1 of col scol)
    // B-fragments persist across iters; phantom lanes keep zeros
    f16x8 p0 = {}, p1 = {}, q0 = {}, q1 = {};

#define ITER(TT, CUR)                                                            \
  {                                                                              \
    const bool active = isA ? ((TT) < T_STEPS) : ((TT) >= 1);                    \
    if (active) {                                                                \
      if (realc) {   /* only real-sample columns read: halves LDS delivery */    \
        p0 = *(const f16x8*)rp[CUR][0];                                          \
        p1 = *(const f16x8*)rp[CUR][1];                                          \
        q0 = *(const f16x8*)rq[CUR][0];                                          \
        q1 = *(const f16x8*)rq[CUR][1];                                          \
      }                                                                          \
      __builtin_amdgcn_s_setprio(1);                                             \
      f32x4 aR  = MFMA(ar[0], p0, bR4);                                          \
      f32x4 aZ  = MFMA(az[0], p0, bZ4);                                          \
      f32x4 aNi = MFMA(ani[0], p0, bNi4);                                        \
      f32x4 aNh = MFMA(anh[0], q0, bNh4);                                        \
      aR  = MFMA(ar[1], p1, aR);   aR  = MFMA(ar[2], q0, aR);                    \
      aR  = MFMA(ar[3], q1, aR);                                                 \
      aZ  = MFMA(az[1], p1, aZ);   aZ  = MFMA(az[2], q0, aZ);                    \
      aZ  = MFMA(az[3], q1, aZ);                                                 \
      aNi = MFMA(ani[1], p1, aNi);                                               \
      aNh = MFMA(anh[1], q1, aNh);                                               \
      __builtin_amdgcn_s_setprio(0);                                             \
      /* repack: phantom-col lanes take rows {2,3} of col i16-8 via dpp ror8 */  \
      float vR0  = realc ? aR[0]  : dpp_ror8(aR[2]);                             \
      float vR1  = realc ? aR[1]  : dpp_ror8(aR[3]);                             \
      float vZ0  = realc ? aZ[0]  : dpp_ror8(aZ[2]);                             \
      float vZ1  = realc ? aZ[1]  : dpp_ror8(aZ[3]);                             \
      float vNi0 = realc ? aNi[0] : dpp_ror8(aNi[2]);                            \
      float vNi1 = realc ? aNi[1] : dpp_ror8(aNi[3]);                            \
      float vNh0 = realc ? aNh[0] : dpp_ror8(aNh[2]);                            \
      float vNh1 = realc ? aNh[1] : dpp_ror8(aNh[3]);                            \
      {                                                                          \
        float rg0 = __builtin_amdgcn_rcpf(1.0f + __builtin_amdgcn_exp2f(vR0));   \
        float zg0 = __builtin_amdgcn_rcpf(1.0f + __builtin_amdgcn_exp2f(vZ0));   \
        float e20 = __builtin_amdgcn_exp2f(fmaf(rg0, vNh0, vNi0));               \
        float ng0 = fmaf(-2.0f, __builtin_amdgcn_rcpf(1.0f + e20), 1.0f);        \
        hr0 = fmaf(zg0, hr0 - ng0, ng0);                                         \
        float rg1 = __builtin_amdgcn_rcpf(1.0f + __builtin_amdgcn_exp2f(vR1));   \
        float zg1 = __builtin_amdgcn_rcpf(1.0f + __builtin_amdgcn_exp2f(vZ1));   \
        float e21 = __builtin_amdgcn_exp2f(fmaf(rg1, vNh1, vNi1));               \
        float ng1 = fmaf(-2.0f, __builtin_amdgcn_rcpf(1.0f + e21), 1.0f);        \
        hr1 = fmaf(zg1, hr1 - ng1, ng1);                                         \
      }                                                                          \
      *(unsigned*)wd[CUR] = pkh(hr0, hr1);                                       \
    }                                                                            \
    if (tid < 256 && (TT) < T_STEPS) {                                           \
      *(unsigned*)sa[CUR] = pkh(PF.x, PF.y);                                     \
      PF = *(const float2*)xnext;                                                \
      xnext += ((TT) <= T_STEPS - 4) ? HID : 0;                                  \
    }                                                                            \
    BAR();                                                                       \
  }

    for (int t = 0; t < T_STEPS; t += 2) {
        ITER(t, 0)
        ITER(t + 1, 1)
    }
    ITER(T_STEPS, 0)      // drain: layer 2 computes h2(511)
#undef ITER

    // final FC from h2b[1]
    if (tid < 64) {
        const int s = tid >> 3, a = tid & 7;
        float acc = fc_b[a];
#pragma unroll
        for (int j = 0; j < HID; ++j) {
            _Float16 hv = *(_Float16*)swz(h2b[1], s, j * 2);
            acc = fmaf((float)hv, fc_w[a * HID + j], acc);
        }
        out[(size_t)(b0 + s) * 8 + a] = acc;
    }
}

extern "C" void kernel_launch(void* const* d_in, const int* in_sizes, int n_in,
                              void* d_out, int out_size, void* d_ws, size_t ws_size,
                              hipStream_t stream) {
    (void)in_sizes; (void)n_in; (void)d_ws; (void)ws_size; (void)out_size;
    const float* state = (const float*)d_in[0];
    const float* w_ih1 = (const float*)d_in[1];
    const float* w_hh1 = (const float*)d_in[2];
    const float* b_ih1 = (const float*)d_in[3];
    const float* b_hh1 = (const float*)d_in[4];
    const float* w_ih2 = (const float*)d_in[5];
    const float* w_hh2 = (const float*)d_in[6];
    const float* b_ih2 = (const float*)d_in[7];
    const float* b_hh2 = (const float*)d_in[8];
    const float* fc_w  = (const float*)d_in[9];
    const float* fc_b  = (const float*)d_in[10];
    float* out = (float*)d_out;

    dim3 grid(2048 / SPB);   // 256 blocks -> 1 per CU, 8 waves = 2/SIMD
    dim3 block(NT);
    gru2_h16<<<grid, block, 0, stream>>>(state,
                                         w_ih1, w_hh1, b_ih1, b_hh1,
                                         w_ih2, w_hh2, b_ih2, b_hh2,
                                         fc_w, fc_b, out);
}